// Round 2
// baseline (1719.316 us; speedup 1.0000x reference)
//
#include <hip/hip_runtime.h>
#include <hip/hip_bf16.h>

// Problem: N=32 time, 32x32 grid, C=64 (H=4 heads x D=16), K=3x3 spatial, T=3 time,
// M=27 offsets, 2 layers. All inputs/outputs are FP32 (per reference dtypes);
// comparison is done in bf16 space by the harness. Compute in fp32.

// ---------------- BatchNorm batch stats (1 block) ----------------
__global__ void bn_stats_kernel(const float* __restrict__ x,
                                float* __restrict__ stats) {
    __shared__ float red[256][6];
    int tid = threadIdx.x;
    float s0 = 0, s1 = 0, s2 = 0, q0 = 0, q1 = 0, q2 = 0;
    for (int i = tid; i < 32768; i += 256) {
        float v0 = x[i * 3 + 0];
        float v1 = x[i * 3 + 1];
        float v2 = x[i * 3 + 2];
        s0 += v0; s1 += v1; s2 += v2;
        q0 += v0 * v0; q1 += v1 * v1; q2 += v2 * v2;
    }
    red[tid][0] = s0; red[tid][1] = s1; red[tid][2] = s2;
    red[tid][3] = q0; red[tid][4] = q1; red[tid][5] = q2;
    __syncthreads();
    for (int w = 128; w > 0; w >>= 1) {
        if (tid < w) {
            #pragma unroll
            for (int f = 0; f < 6; ++f) red[tid][f] += red[tid + w][f];
        }
        __syncthreads();
    }
    if (tid < 3) {
        float mean = red[0][tid] * (1.0f / 32768.0f);
        float var  = red[0][tid + 3] * (1.0f / 32768.0f) - mean * mean;
        stats[tid]     = mean;
        stats[tid + 3] = rsqrtf(var + 1e-5f);
    }
}

// ---------------- h0 = normalize(x) @ W_in + b_in ----------------
__global__ void init_h_kernel(const float* __restrict__ x,
                              const float* __restrict__ W_in,
                              const float* __restrict__ b_in,
                              const float* __restrict__ stats,
                              float* __restrict__ h) {
    int idx  = blockIdx.x * 256 + threadIdx.x;   // cell*64 + c, 2M total
    int c    = idx & 63;
    int cell = idx >> 6;
    float acc = b_in[c];
    #pragma unroll
    for (int f = 0; f < 3; ++f) {
        float xn = (x[cell * 3 + f] - stats[f]) * stats[f + 3];
        acc += xn * W_in[f * 64 + c];
    }
    h[idx] = acc;
}

// Per-thread 1x4 output tile of a [.,64]x[64,64] GEMM.
// Hrow: LDS row (64 f32). W: global f32, row-major [64][64], column offset pre-applied.
__device__ __forceinline__ float4 gemm4(const float* __restrict__ Hrow,
                                        const float* __restrict__ W,
                                        float4 acc) {
    #pragma unroll
    for (int c = 0; c < 64; c += 4) {
        float4 hv = *(const float4*)(Hrow + c);
        float4 w0 = *(const float4*)(W + (c + 0) * 64);
        float4 w1 = *(const float4*)(W + (c + 1) * 64);
        float4 w2 = *(const float4*)(W + (c + 2) * 64);
        float4 w3 = *(const float4*)(W + (c + 3) * 64);
        acc.x += hv.x * w0.x + hv.y * w1.x + hv.z * w2.x + hv.w * w3.x;
        acc.y += hv.x * w0.y + hv.y * w1.y + hv.z * w2.y + hv.w * w3.y;
        acc.z += hv.x * w0.z + hv.y * w1.z + hv.z * w2.z + hv.w * w3.z;
        acc.w += hv.x * w0.w + hv.y * w1.w + hv.z * w2.w + hv.w * w3.w;
    }
    return acc;
}

// ---------------- fused attention layer ----------------
// grid (b=32, a=32, nb=2); block 256. Each block: spatial column (a,b), 16 time rows.
// Thread tid: ln = tid>>4 (local n), g = tid&15 (channel group c0=4g, head hh=g>>2).
__global__ __launch_bounds__(256, 3)
void layer_kernel(const float* __restrict__ hin,
                  float* __restrict__ hout,
                  const float* __restrict__ Wq,   // [64][64]
                  const float* __restrict__ bq,   // [64]
                  const float* __restrict__ Wk,   // [27][64][64]
                  const float* __restrict__ bk,   // [27][64]
                  const float* __restrict__ Wv,
                  const float* __restrict__ bv) {
    __shared__ float Hn[9][18][64];   // [spatial offset][time row (gn = nb*16-1+r)][c]
    __shared__ float Sc[16][4][28];   // scores [ln][head][m]

    const int tid = threadIdx.x;
    const int b   = blockIdx.x;
    const int a   = blockIdx.y;
    const int nb  = blockIdx.z;

    // Stage 3x3 spatial x 18-time halo; zero rows for any OOB (time-OOB rows give
    // k/v = bias exactly as the reference's zero-padded time unfold; spatial-OOB
    // rows are masked later anyway).
    for (int i = tid; i < 9 * 18 * 64; i += 256) {
        int c    = i & 63;
        int rest = i >> 6;
        int r    = rest % 18;
        int sp   = rest / 18;
        int di = sp / 3, dj = sp % 3;
        int aa = a + di - 1, bb = b + dj - 1;
        int n  = nb * 16 + r - 1;
        float v = 0.0f;
        if ((unsigned)n < 32u && (unsigned)aa < 32u && (unsigned)bb < 32u)
            v = hin[((n * 32 + aa) * 32 + bb) * 64 + c];
        Hn[sp][r][c] = v;
    }
    __syncthreads();

    const int g  = tid & 15;
    const int ln = tid >> 4;
    const int c0 = g * 4;
    const int hh = g >> 2;

    // Q projection (center cell): q[ln][c0..c0+3] kept in registers.
    float4 qv = make_float4(bq[c0], bq[c0 + 1], bq[c0 + 2], bq[c0 + 3]);
    qv = gemm4(&Hn[4][ln + 1][0], Wq + c0, qv);

    // K pass: per offset m=(t,di,dj), GEMM -> partial dot with q -> 4-lane shuffle
    // reduce (lanes g=4*hh..4*hh+3 hold d=0..15 of head hh) -> score in LDS.
    for (int m = 0; m < 27; ++m) {
        int t  = m / 9;
        int sp = m - t * 9;
        int di = sp / 3, dj = sp - di * 3;
        bool valid = ((unsigned)(a + di - 1) < 32u) && ((unsigned)(b + dj - 1) < 32u);
        float sval = -1e30f;
        if (valid) {
            float4 kv = make_float4(bk[m * 64 + c0],     bk[m * 64 + c0 + 1],
                                    bk[m * 64 + c0 + 2], bk[m * 64 + c0 + 3]);
            kv = gemm4(&Hn[sp][ln + t][0], Wk + m * 4096 + c0, kv);
            float partial = kv.x * qv.x + kv.y * qv.y + kv.z * qv.z + kv.w * qv.w;
            partial += __shfl_xor(partial, 1);
            partial += __shfl_xor(partial, 2);
            sval = partial;
        }
        if ((g & 3) == 0) Sc[ln][hh][m] = sval;
    }
    __syncthreads();

    // Softmax over 27 (fp32, max-subtracted), recomputed per thread from LDS.
    float mx = -1e30f;
    #pragma unroll
    for (int m = 0; m < 27; ++m) mx = fmaxf(mx, Sc[ln][hh][m]);
    float ssum = 0.0f;
    #pragma unroll
    for (int m = 0; m < 27; ++m) ssum += __expf(Sc[ln][hh][m] - mx);
    float sinv = 1.0f / ssum;

    // V pass: thread's V-GEMM outputs ARE its attention-output channels -> pure
    // register accumulation, no barriers.
    float ox = 0, oy = 0, oz = 0, ow = 0;
    for (int m = 0; m < 27; ++m) {
        int t  = m / 9;
        int sp = m - t * 9;
        int di = sp / 3, dj = sp - di * 3;
        bool valid = ((unsigned)(a + di - 1) < 32u) && ((unsigned)(b + dj - 1) < 32u);
        if (!valid) continue;
        float wgt = __expf(Sc[ln][hh][m] - mx) * sinv;
        float4 vv = make_float4(bv[m * 64 + c0],     bv[m * 64 + c0 + 1],
                                bv[m * 64 + c0 + 2], bv[m * 64 + c0 + 3]);
        vv = gemm4(&Hn[sp][ln + t][0], Wv + m * 4096 + c0, vv);
        ox += wgt * vv.x; oy += wgt * vv.y; oz += wgt * vv.z; ow += wgt * vv.w;
    }

    // Residual + store.
    int gn = nb * 16 + ln;
    float4 res = *(const float4*)&Hn[4][ln + 1][c0];
    float4 o = make_float4(ox + res.x, oy + res.y, oz + res.z, ow + res.w);
    *(float4*)&hout[((gn * 32 + a) * 32 + b) * 64 + c0] = o;
}

// ---------------- out = h @ W_out + b_out ----------------
__global__ void out_proj_kernel(const float* __restrict__ h,
                                const float* __restrict__ W_out,
                                const float* __restrict__ b_out,
                                float* __restrict__ out) {
    int cell = blockIdx.x * 256 + threadIdx.x;   // 32768 cells
    float a0 = b_out[0], a1 = b_out[1], a2 = b_out[2];
    const float* hr = h + cell * 64;
    #pragma unroll 8
    for (int c = 0; c < 64; ++c) {
        float hv = hr[c];
        a0 += hv * W_out[c * 3 + 0];
        a1 += hv * W_out[c * 3 + 1];
        a2 += hv * W_out[c * 3 + 2];
    }
    out[cell * 3 + 0] = a0;
    out[cell * 3 + 1] = a1;
    out[cell * 3 + 2] = a2;
}

extern "C" void kernel_launch(void* const* d_in, const int* in_sizes, int n_in,
                              void* d_out, int out_size, void* d_ws, size_t ws_size,
                              hipStream_t stream) {
    const float* x     = (const float*)d_in[0];
    const float* W_in  = (const float*)d_in[1];
    const float* b_in  = (const float*)d_in[2];
    const float* W_out = (const float*)d_in[3];
    const float* b_out = (const float*)d_in[4];
    const float* Wq    = (const float*)d_in[5];
    const float* bq    = (const float*)d_in[6];
    const float* Wk    = (const float*)d_in[7];
    const float* bk    = (const float*)d_in[8];
    const float* Wv    = (const float*)d_in[9];
    const float* bv    = (const float*)d_in[10];

    float* ws    = (float*)d_ws;
    float* stats = ws;                     // 64 floats (mean[3], rstd[3])
    float* h0    = ws + 64;                // 32768*64
    float* h1    = h0 + 2097152;           // total ws use ~16.8 MB

    bn_stats_kernel<<<1, 256, 0, stream>>>(x, stats);
    init_h_kernel<<<8192, 256, 0, stream>>>(x, W_in, b_in, stats, h0);

    dim3 grid(32, 32, 2);
    layer_kernel<<<grid, 256, 0, stream>>>(h0, h1, Wq, bq, Wk, bk, Wv, bv);
    layer_kernel<<<grid, 256, 0, stream>>>(h1, h0, Wq + 4096, bq + 64,
                                           Wk + 110592, bk + 1728,
                                           Wv + 110592, bv + 1728);
    out_proj_kernel<<<128, 256, 0, stream>>>(h0, W_out, b_out, (float*)d_out);
}

// Round 3
// 238.966 us; speedup vs baseline: 7.1948x; 7.1948x over previous
//
#include <hip/hip_runtime.h>
#include <hip/hip_bf16.h>

// N=32 time, 32x32 grid, C=64 (H=4 x D=16), 3x3x3 offsets (M=27), 2 layers.
// All inputs/outputs fp32. R3: MFMA bf16 path. Weight fragments are read once
// per tile (kills the 16x redundant L2 reads that bound R2 at 870us/layer).

typedef short short8_t __attribute__((ext_vector_type(8)));
typedef float floatx4 __attribute__((ext_vector_type(4)));

__device__ __forceinline__ short f2bs(float f) {
    __hip_bfloat16 h = __float2bfloat16(f);
    return *reinterpret_cast<short*>(&h);
}

// ---------------- BatchNorm batch stats (1 block) ----------------
__global__ void bn_stats_kernel(const float* __restrict__ x,
                                float* __restrict__ stats) {
    __shared__ float red[256][6];
    int tid = threadIdx.x;
    float s0 = 0, s1 = 0, s2 = 0, q0 = 0, q1 = 0, q2 = 0;
    for (int i = tid; i < 32768; i += 256) {
        float v0 = x[i * 3 + 0];
        float v1 = x[i * 3 + 1];
        float v2 = x[i * 3 + 2];
        s0 += v0; s1 += v1; s2 += v2;
        q0 += v0 * v0; q1 += v1 * v1; q2 += v2 * v2;
    }
    red[tid][0] = s0; red[tid][1] = s1; red[tid][2] = s2;
    red[tid][3] = q0; red[tid][4] = q1; red[tid][5] = q2;
    __syncthreads();
    for (int w = 128; w > 0; w >>= 1) {
        if (tid < w) {
            #pragma unroll
            for (int f = 0; f < 6; ++f) red[tid][f] += red[tid + w][f];
        }
        __syncthreads();
    }
    if (tid < 3) {
        float mean = red[0][tid] * (1.0f / 32768.0f);
        float var  = red[0][tid + 3] * (1.0f / 32768.0f) - mean * mean;
        stats[tid]     = mean;
        stats[tid + 3] = rsqrtf(var + 1e-5f);
    }
}

// ---------------- h0 = normalize(x) @ W_in + b_in ----------------
__global__ void init_h_kernel(const float* __restrict__ x,
                              const float* __restrict__ W_in,
                              const float* __restrict__ b_in,
                              const float* __restrict__ stats,
                              float* __restrict__ h) {
    int idx  = blockIdx.x * 256 + threadIdx.x;
    int c    = idx & 63;
    int cell = idx >> 6;
    float acc = b_in[c];
    #pragma unroll
    for (int f = 0; f < 3; ++f) {
        float xn = (x[cell * 3 + f] - stats[f]) * stats[f + 3];
        acc += xn * W_in[f * 64 + c];
    }
    h[idx] = acc;
}

// ---------------- repack W (fp32 [64k][64n]) -> bf16 B-fragment layout -------
// dst[mat][((kk*4+nt)*64+lane)*8 + j] = W[mat][kk*32 + (lane>>4)*8 + j][nt*16 + (lane&15)]
__global__ void repack_w(const float* __restrict__ src, short* __restrict__ dst,
                         int nmat) {
    int t = blockIdx.x * 256 + threadIdx.x;
    if (t >= nmat * 512) return;
    int mat  = t >> 9;
    int rem  = t & 511;
    int kk   = rem >> 8;
    int nt   = (rem >> 6) & 3;
    int lane = rem & 63;
    int krow = kk * 32 + (lane >> 4) * 8;
    int col  = nt * 16 + (lane & 15);
    const float* W = src + mat * 4096;
    short8_t v;
    #pragma unroll
    for (int j = 0; j < 8; ++j) v[j] = f2bs(W[(krow + j) * 64 + col]);
    *(short8_t*)&dst[(size_t)mat * 4096 + ((kk * 4 + nt) * 64 + lane) * 8] = v;
}

// ---------------- fused attention layer (MFMA) ----------------
// grid (b=32, a=32); block 256 = 4 waves; wave w = head w (col-tile w).
// C-frag mapping (m89): col = lane&15, row = (lane>>4)*4 + reg (+16 for tile1).
// A-frag: A[m=lane&15][k=(lane>>4)*8+j]; B symmetric, pre-repacked.
__global__ __launch_bounds__(256, 2)
void layer_mfma(const float* __restrict__ hin,
                float* __restrict__ hout,
                const short* __restrict__ wqB, const float* __restrict__ bq,
                const short* __restrict__ wkB, const float* __restrict__ bk,
                const short* __restrict__ wvB, const float* __restrict__ bv) {
    __shared__ short HnS[9 * 34 * 72];   // halo, bf16, pitch 72 (2-way-free b128)
    __shared__ float Sc[4 * 872];        // [head][m(27)*32 rows], pitch 872 (bank-skewed)

    const int tid = threadIdx.x;
    const int b = blockIdx.x, a = blockIdx.y;

    // ---- stage halo (fp32 -> bf16); OOB rows zeroed (time-OOB => k,v = bias) ----
    for (int i = tid; i < 9 * 34 * 16; i += 256) {
        int c4 = (i & 15) * 4;
        int rr = i >> 4;
        int sp = rr / 34;
        int r  = rr - sp * 34;
        int aa = a + sp / 3 - 1;
        int bb = b + sp % 3 - 1;
        int n  = r - 1;
        short4 sv = make_short4(0, 0, 0, 0);
        if ((unsigned)n < 32u && (unsigned)aa < 32u && (unsigned)bb < 32u) {
            float4 v = *(const float4*)&hin[(((n * 32 + aa) * 32 + bb) << 6) + c4];
            sv = make_short4(f2bs(v.x), f2bs(v.y), f2bs(v.z), f2bs(v.w));
        }
        *(short4*)&HnS[(sp * 34 + r) * 72 + c4] = sv;
    }
    __syncthreads();

    const int lane = tid & 63;
    const int w    = tid >> 6;       // head
    const int e    = lane & 15;
    const int q    = lane >> 4;
    const int aoff = q * 8;
    const int scb  = w * 872;

    // ---- Q projection (center cell, rows n=0..31) ----
    floatx4 q0 = {0, 0, 0, 0}, q1 = {0, 0, 0, 0};
    #pragma unroll
    for (int kk = 0; kk < 2; ++kk) {
        short8_t bf = *(const short8_t*)&wqB[((kk * 4 + w) * 64 + lane) * 8];
        short8_t a0 = *(const short8_t*)&HnS[(4 * 34 + e + 1) * 72 + kk * 32 + aoff];
        short8_t a1 = *(const short8_t*)&HnS[(4 * 34 + 17 + e) * 72 + kk * 32 + aoff];
        q0 = __builtin_amdgcn_mfma_f32_16x16x32_bf16(a0, bf, q0, 0, 0, 0);
        q1 = __builtin_amdgcn_mfma_f32_16x16x32_bf16(a1, bf, q1, 0, 0, 0);
    }
    const float bqv = bq[w * 16 + e];
    float qv0[4], qv1[4];
    #pragma unroll
    for (int i = 0; i < 4; ++i) { qv0[i] = q0[i] + bqv; qv1[i] = q1[i] + bqv; }

    // ---- K pass: scores ----
    for (int m = 0; m < 27; ++m) {
        const int t = m / 9, sp = m - t * 9;
        const bool valid = ((unsigned)(a + sp / 3 - 1) < 32u) &&
                           ((unsigned)(b + sp % 3 - 1) < 32u);
        float w0 = -1e30f, w1 = -1e30f;
        if (valid) {                              // wave-uniform branch
            floatx4 k0 = {0, 0, 0, 0}, k1 = {0, 0, 0, 0};
            const int rbase = (sp * 34 + e + t) * 72;
            #pragma unroll
            for (int kk = 0; kk < 2; ++kk) {
                short8_t bf = *(const short8_t*)&wkB[m * 4096 + ((kk * 4 + w) * 64 + lane) * 8];
                short8_t a0 = *(const short8_t*)&HnS[rbase + kk * 32 + aoff];
                short8_t a1 = *(const short8_t*)&HnS[rbase + 16 * 72 + kk * 32 + aoff];
                k0 = __builtin_amdgcn_mfma_f32_16x16x32_bf16(a0, bf, k0, 0, 0, 0);
                k1 = __builtin_amdgcn_mfma_f32_16x16x32_bf16(a1, bf, k1, 0, 0, 0);
            }
            const float bkv = bk[m * 64 + w * 16 + e];
            float p0 = (k0[0] + bkv) * qv0[0], p1 = (k0[1] + bkv) * qv0[1];
            float p2 = (k0[2] + bkv) * qv0[2], p3 = (k0[3] + bkv) * qv0[3];
            float p4 = (k1[0] + bkv) * qv1[0], p5 = (k1[1] + bkv) * qv1[1];
            float p6 = (k1[2] + bkv) * qv1[2], p7 = (k1[3] + bkv) * qv1[3];
            // reduce-scatter over the 16 e-lanes (5 shuffles per tile-pair)
            bool b0 = (e & 1) != 0;
            float s0 = b0 ? p0 : p2, s1 = b0 ? p1 : p3;
            float s4 = b0 ? p4 : p6, s5 = b0 ? p5 : p7;
            float r0 = __shfl_xor(s0, 1), r1 = __shfl_xor(s1, 1);
            float r4 = __shfl_xor(s4, 1), r5 = __shfl_xor(s5, 1);
            float u0 = (b0 ? p2 : p0) + r0, u1 = (b0 ? p3 : p1) + r1;
            float u4 = (b0 ? p6 : p4) + r4, u5 = (b0 ? p7 : p5) + r5;
            bool b1 = (e & 2) != 0;
            float s2 = b1 ? u0 : u1, s6 = b1 ? u4 : u5;
            float r2 = __shfl_xor(s2, 2), r6 = __shfl_xor(s6, 2);
            w0 = (b1 ? u1 : u0) + r2;
            w1 = (b1 ? u5 : u4) + r6;
            w0 += __shfl_xor(w0, 4);  w0 += __shfl_xor(w0, 8);
            w1 += __shfl_xor(w1, 4);  w1 += __shfl_xor(w1, 8);
        }
        if (e < 8) {  // lanes e,e^4,e^8,e^12 hold identical sums; e<4 tile0, 4..7 tile1
            int rl  = 2 * (e & 1) + ((e >> 1) & 1);
            int row = q * 4 + rl + ((e < 4) ? 0 : 16);
            Sc[scb + m * 32 + row] = (e < 4) ? w0 : w1;
        }
    }
    __syncthreads();

    // ---- softmax over 27 per (head,row): 128 threads ----
    if (tid < 128) {
        float* sc = &Sc[(tid >> 5) * 872 + (tid & 31)];
        float ex[27];
        float mx = -1e30f;
        #pragma unroll
        for (int m = 0; m < 27; ++m) { ex[m] = sc[m * 32]; mx = fmaxf(mx, ex[m]); }
        float ssum = 0.f;
        #pragma unroll
        for (int m = 0; m < 27; ++m) { ex[m] = __expf(ex[m] - mx); ssum += ex[m]; }
        float inv = 1.0f / ssum;
        #pragma unroll
        for (int m = 0; m < 27; ++m) sc[m * 32] = ex[m] * inv;
    }
    __syncthreads();

    // ---- V pass: weighted accumulate ----
    floatx4 o0 = {0, 0, 0, 0}, o1 = {0, 0, 0, 0};
    for (int m = 0; m < 27; ++m) {
        const int t = m / 9, sp = m - t * 9;
        if (!(((unsigned)(a + sp / 3 - 1) < 32u) &&
              ((unsigned)(b + sp % 3 - 1) < 32u))) continue;
        floatx4 v0 = {0, 0, 0, 0}, v1 = {0, 0, 0, 0};
        const int rbase = (sp * 34 + e + t) * 72;
        #pragma unroll
        for (int kk = 0; kk < 2; ++kk) {
            short8_t bf = *(const short8_t*)&wvB[m * 4096 + ((kk * 4 + w) * 64 + lane) * 8];
            short8_t a0 = *(const short8_t*)&HnS[rbase + kk * 32 + aoff];
            short8_t a1 = *(const short8_t*)&HnS[rbase + 16 * 72 + kk * 32 + aoff];
            v0 = __builtin_amdgcn_mfma_f32_16x16x32_bf16(a0, bf, v0, 0, 0, 0);
            v1 = __builtin_amdgcn_mfma_f32_16x16x32_bf16(a1, bf, v1, 0, 0, 0);
        }
        const float bvv = bv[m * 64 + w * 16 + e];
        floatx4 g0 = *(const floatx4*)&Sc[scb + m * 32 + q * 4];
        floatx4 g1 = *(const floatx4*)&Sc[scb + m * 32 + q * 4 + 16];
        #pragma unroll
        for (int i = 0; i < 4; ++i) {
            o0[i] += g0[i] * (v0[i] + bvv);
            o1[i] += g1[i] * (v1[i] + bvv);
        }
    }

    // ---- residual (fp32 from global, not bf16 LDS) + store ----
    const int c = w * 16 + e;
    #pragma unroll
    for (int i = 0; i < 4; ++i) {
        int n0 = q * 4 + i;
        int i0 = (((n0 * 32 + a) * 32 + b) << 6) + c;
        hout[i0] = o0[i] + hin[i0];
        int n1 = n0 + 16;
        int i1 = (((n1 * 32 + a) * 32 + b) << 6) + c;
        hout[i1] = o1[i] + hin[i1];
    }
}

// ---------------- out = h @ W_out + b_out ----------------
__global__ void out_proj_kernel(const float* __restrict__ h,
                                const float* __restrict__ W_out,
                                const float* __restrict__ b_out,
                                float* __restrict__ out) {
    int cell = blockIdx.x * 256 + threadIdx.x;
    float a0 = b_out[0], a1 = b_out[1], a2 = b_out[2];
    const float* hr = h + cell * 64;
    #pragma unroll 8
    for (int c = 0; c < 64; ++c) {
        float hv = hr[c];
        a0 += hv * W_out[c * 3 + 0];
        a1 += hv * W_out[c * 3 + 1];
        a2 += hv * W_out[c * 3 + 2];
    }
    out[cell * 3 + 0] = a0;
    out[cell * 3 + 1] = a1;
    out[cell * 3 + 2] = a2;
}

extern "C" void kernel_launch(void* const* d_in, const int* in_sizes, int n_in,
                              void* d_out, int out_size, void* d_ws, size_t ws_size,
                              hipStream_t stream) {
    const float* x     = (const float*)d_in[0];
    const float* W_in  = (const float*)d_in[1];
    const float* b_in  = (const float*)d_in[2];
    const float* W_out = (const float*)d_in[3];
    const float* b_out = (const float*)d_in[4];
    const float* Wq    = (const float*)d_in[5];
    const float* bq    = (const float*)d_in[6];
    const float* Wk    = (const float*)d_in[7];
    const float* bk    = (const float*)d_in[8];
    const float* Wv    = (const float*)d_in[9];
    const float* bv    = (const float*)d_in[10];

    float* ws    = (float*)d_ws;
    float* stats = ws;                         // 64 floats
    float* h0    = ws + 64;                    // 2M floats
    float* h1    = h0 + 2097152;               // 2M floats
    short* wqB   = (short*)(h1 + 2097152);     // 2  x 4096 bf16
    short* wkB   = wqB + 2 * 4096;             // 54 x 4096 bf16
    short* wvB   = wkB + 54 * 4096;            // 54 x 4096 bf16  (~17.7 MB total)

    bn_stats_kernel<<<1, 256, 0, stream>>>(x, stats);
    init_h_kernel<<<8192, 256, 0, stream>>>(x, W_in, b_in, stats, h0);
    repack_w<<<4, 256, 0, stream>>>(Wq, wqB, 2);
    repack_w<<<108, 256, 0, stream>>>(Wk, wkB, 54);
    repack_w<<<108, 256, 0, stream>>>(Wv, wvB, 54);

    dim3 grid(32, 32);
    layer_mfma<<<grid, 256, 0, stream>>>(h0, h1, wqB, bq, wkB, bk, wvB, bv);
    layer_mfma<<<grid, 256, 0, stream>>>(h1, h0, wqB + 4096, bq + 64,
                                         wkB + 27 * 4096, bk + 1728,
                                         wvB + 27 * 4096, bv + 1728);
    out_proj_kernel<<<128, 256, 0, stream>>>(h0, W_out, b_out, (float*)d_out);
}

// Round 4
// 183.426 us; speedup vs baseline: 9.3733x; 1.3028x over previous
//
#include <hip/hip_runtime.h>
#include <hip/hip_bf16.h>

// N=32 time, 32x32 grid, C=64 (H=4 x D=16), 3x3x3 offsets (M=27), 2 layers.
// R4: nb-split (16 rows/block, 28KB LDS -> 5 blocks/CU), XOR-swizzled halo
// (conflict-free ds b128), init_h fused into layer1 staging (h0 computed from
// x-halo), out_proj fused into layer2 epilogue, bn via atomic partial sums.

typedef short short8_t __attribute__((ext_vector_type(8)));
typedef float floatx4 __attribute__((ext_vector_type(4)));

__device__ __forceinline__ short f2bs(float f) {
    __hip_bfloat16 h = __float2bfloat16(f);
    return *reinterpret_cast<short*>(&h);
}
// swizzled halo addressing: row = sp*18 + r (162 rows x 64 shorts), 8 chunks of 8 shorts
__device__ __forceinline__ int hn_idx(int rowid, int chunk) {
    return rowid * 64 + ((chunk ^ (rowid & 7)) << 3);
}

// ---------------- BN partial sums (32 blocks, atomic accumulate) ----------------
__global__ void bn_partial(const float* __restrict__ x, float* __restrict__ sums) {
    int t = blockIdx.x * 256 + threadIdx.x;        // 8192 threads x 12 floats = 98304
    const float4* x4 = (const float4*)x;
    float4 v0 = x4[t * 3 + 0], v1 = x4[t * 3 + 1], v2 = x4[t * 3 + 2];
    float s0 = v0.x + v0.w + v1.z + v2.y;
    float s1 = v0.y + v1.x + v1.w + v2.z;
    float s2 = v0.z + v1.y + v2.x + v2.w;
    float q0 = v0.x*v0.x + v0.w*v0.w + v1.z*v1.z + v2.y*v2.y;
    float q1 = v0.y*v0.y + v1.x*v1.x + v1.w*v1.w + v2.z*v2.z;
    float q2 = v0.z*v0.z + v1.y*v1.y + v2.x*v2.x + v2.w*v2.w;
    float v[6] = {s0, s1, s2, q0, q1, q2};
    #pragma unroll
    for (int i = 0; i < 6; ++i) {
        #pragma unroll
        for (int off = 1; off < 64; off <<= 1) v[i] += __shfl_xor(v[i], off);
    }
    __shared__ float part[4][6];
    if ((threadIdx.x & 63) == 0) {
        #pragma unroll
        for (int i = 0; i < 6; ++i) part[threadIdx.x >> 6][i] = v[i];
    }
    __syncthreads();
    if (threadIdx.x < 6) {
        float acc = part[0][threadIdx.x] + part[1][threadIdx.x] +
                    part[2][threadIdx.x] + part[3][threadIdx.x];
        atomicAdd(&sums[threadIdx.x], acc);
    }
}

// ---------------- repack all W (fp32 [64k][64n]) -> bf16 B-fragment layout ------
// mats: 0..1 Wq(l), 2..55 Wk(l,m), 56..109 Wv(l,m)
__global__ void repack_all(const float* __restrict__ Wq, const float* __restrict__ Wk,
                           const float* __restrict__ Wv, short* __restrict__ dst) {
    int t = blockIdx.x * 256 + threadIdx.x;
    if (t >= 110 * 512) return;
    int mat  = t >> 9;
    int rem  = t & 511;
    int kk   = rem >> 8;
    int nt   = (rem >> 6) & 3;
    int lane = rem & 63;
    int krow = kk * 32 + (lane >> 4) * 8;
    int col  = nt * 16 + (lane & 15);
    const float* W;
    if (mat < 2)       W = Wq + mat * 4096;
    else if (mat < 56) W = Wk + (mat - 2) * 4096;
    else               W = Wv + (mat - 56) * 4096;
    short8_t v;
    #pragma unroll
    for (int j = 0; j < 8; ++j) v[j] = f2bs(W[(krow + j) * 64 + col]);
    *(short8_t*)&dst[(size_t)mat * 4096 + ((kk * 4 + nt) * 64 + lane) * 8] = v;
}

// ---------------- fused attention layer ----------------
// grid (b=32, a=32, nb=2); block 256 = 4 waves; wave w = head w.
// FIRST: stage h0 computed from x-halo; residual recomputed from x; writes h1 f32+bf16.
// !FIRST: stage from hbf; residual from hres f32; fused out-projection to d_out.
template <bool FIRST>
__global__ __launch_bounds__(256, 5)
void layer_fused(const float* __restrict__ x, const float* __restrict__ sums,
                 const float* __restrict__ W_in, const float* __restrict__ b_in,
                 const float* __restrict__ hres, const short* __restrict__ hbf,
                 float* __restrict__ hout, short* __restrict__ hbfout,
                 const float* __restrict__ Wout, const float* __restrict__ bout,
                 float* __restrict__ out,
                 const short* __restrict__ wqB, const float* __restrict__ bq,
                 const short* __restrict__ wkB, const float* __restrict__ bk,
                 const short* __restrict__ wvB, const float* __restrict__ bv) {
    __shared__ short HnS[162 * 64];   // 20.25 KB, XOR-swizzled
    __shared__ float Sc[4 * 432];     // scores [head][m*16+row]; later overlaid h_final (pitch 68)
    __shared__ float Waux[256];       // FIRST: W_in[3][64]+b_in[64]; else Wout[64*3]+bout

    const int tid = threadIdx.x;
    const int b = blockIdx.x, a = blockIdx.y, nb = blockIdx.z;

    float mean0, mean1, mean2, rs0, rs1, rs2;
    if (FIRST) {
        float s0 = sums[0], s1 = sums[1], s2 = sums[2];
        float t0 = sums[3], t1 = sums[4], t2 = sums[5];
        mean0 = s0 * (1.f/32768.f); mean1 = s1 * (1.f/32768.f); mean2 = s2 * (1.f/32768.f);
        rs0 = rsqrtf(t0 * (1.f/32768.f) - mean0*mean0 + 1e-5f);
        rs1 = rsqrtf(t1 * (1.f/32768.f) - mean1*mean1 + 1e-5f);
        rs2 = rsqrtf(t2 * (1.f/32768.f) - mean2*mean2 + 1e-5f);
        if (tid < 192) Waux[tid] = W_in[tid];
        else           Waux[tid] = b_in[tid - 192];
    } else {
        if (tid < 192)      Waux[tid] = Wout[tid];
        else if (tid < 195) Waux[tid] = bout[tid - 192];
    }
    __syncthreads();

    // ---- stage halo: 162 rows x 8 chunks of 8 bf16 ----
    for (int id = tid; id < 1296; id += 256) {
        int rowid = id >> 3, cc = id & 7;
        int sp = rowid / 18, r = rowid - sp * 18;
        int aa = a + sp / 3 - 1, bb = b + sp % 3 - 1;
        int n  = nb * 16 + r - 1;
        short8_t v = {0, 0, 0, 0, 0, 0, 0, 0};
        if ((unsigned)n < 32u && (unsigned)aa < 32u && (unsigned)bb < 32u) {
            int cell = (n * 32 + aa) * 32 + bb;
            if (FIRST) {
                float xn0 = (x[cell*3+0] - mean0) * rs0;
                float xn1 = (x[cell*3+1] - mean1) * rs1;
                float xn2 = (x[cell*3+2] - mean2) * rs2;
                #pragma unroll
                for (int j = 0; j < 8; ++j) {
                    int c = cc * 8 + j;
                    float h = Waux[192+c] + xn0*Waux[c] + xn1*Waux[64+c] + xn2*Waux[128+c];
                    v[j] = f2bs(h);
                }
            } else {
                v = *(const short8_t*)&hbf[cell * 64 + cc * 8];
            }
        }
        *(short8_t*)&HnS[hn_idx(rowid, cc)] = v;
    }
    __syncthreads();

    const int lane = tid & 63;
    const int w    = tid >> 6;       // head
    const int e    = lane & 15;
    const int q    = lane >> 4;

    // ---- Q projection (center cell sp=4, rows r=e+1) ----
    floatx4 qacc = {0, 0, 0, 0};
    {
        const int rq = 4 * 18 + e + 1;
        #pragma unroll
        for (int kk = 0; kk < 2; ++kk) {
            short8_t bf = *(const short8_t*)&wqB[((kk * 4 + w) * 64 + lane) * 8];
            short8_t af = *(const short8_t*)&HnS[hn_idx(rq, kk * 4 + q)];
            qacc = __builtin_amdgcn_mfma_f32_16x16x32_bf16(af, bf, qacc, 0, 0, 0);
        }
    }
    const float bqv = bq[w * 16 + e];
    float qv[4];
    #pragma unroll
    for (int i = 0; i < 4; ++i) qv[i] = qacc[i] + bqv;

    // ---- K pass: scores ----
    for (int sp = 0; sp < 9; ++sp) {
        const bool valid = ((unsigned)(a + sp / 3 - 1) < 32u) &&
                           ((unsigned)(b + sp % 3 - 1) < 32u);
        #pragma unroll
        for (int t = 0; t < 3; ++t) {
            const int m = t * 9 + sp;
            float v = -1e30f;
            if (valid) {
                floatx4 kacc = {0, 0, 0, 0};
                const int rk = sp * 18 + e + t;
                #pragma unroll
                for (int kk = 0; kk < 2; ++kk) {
                    short8_t bf = *(const short8_t*)&wkB[m * 4096 + ((kk * 4 + w) * 64 + lane) * 8];
                    short8_t af = *(const short8_t*)&HnS[hn_idx(rk, kk * 4 + q)];
                    kacc = __builtin_amdgcn_mfma_f32_16x16x32_bf16(af, bf, kacc, 0, 0, 0);
                }
                const float bkv = bk[m * 64 + w * 16 + e];
                float p0 = (kacc[0] + bkv) * qv[0];
                float p1 = (kacc[1] + bkv) * qv[1];
                float p2 = (kacc[2] + bkv) * qv[2];
                float p3 = (kacc[3] + bkv) * qv[3];
                // reduce-scatter across the 16 e-lanes (4 shuffles)
                bool b0 = (e & 1) != 0;
                float sA = b0 ? p0 : p2, sB = b0 ? p1 : p3;
                float rA = __shfl_xor(sA, 1), rB = __shfl_xor(sB, 1);
                float u0 = (b0 ? p2 : p0) + rA;
                float u1 = (b0 ? p3 : p1) + rB;
                bool b1 = (e & 2) != 0;
                float sC = b1 ? u0 : u1;
                float rC = __shfl_xor(sC, 2);
                v = (b1 ? u1 : u0) + rC;
                v += __shfl_xor(v, 4);
                v += __shfl_xor(v, 8);
            }
            if (e < 4) {
                int rl = 2 * (e & 1) + ((e >> 1) & 1);
                Sc[w * 432 + m * 16 + q * 4 + rl] = v;
            }
        }
    }
    __syncthreads();

    // ---- softmax over 27 per (head,row): 64 threads ----
    if (tid < 64) {
        float* sc = &Sc[(tid >> 4) * 432 + (tid & 15)];
        float ex[27];
        float mx = -1e30f;
        #pragma unroll
        for (int m = 0; m < 27; ++m) { ex[m] = sc[m * 16]; mx = fmaxf(mx, ex[m]); }
        float ssum = 0.f;
        #pragma unroll
        for (int m = 0; m < 27; ++m) { ex[m] = __expf(ex[m] - mx); ssum += ex[m]; }
        float inv = 1.0f / ssum;
        #pragma unroll
        for (int m = 0; m < 27; ++m) sc[m * 16] = ex[m] * inv;
    }
    __syncthreads();

    // ---- V pass ----
    floatx4 o = {0, 0, 0, 0};
    for (int sp = 0; sp < 9; ++sp) {
        if (!(((unsigned)(a + sp / 3 - 1) < 32u) &&
              ((unsigned)(b + sp % 3 - 1) < 32u))) continue;
        #pragma unroll
        for (int t = 0; t < 3; ++t) {
            const int m = t * 9 + sp;
            floatx4 vacc = {0, 0, 0, 0};
            const int rv = sp * 18 + e + t;
            #pragma unroll
            for (int kk = 0; kk < 2; ++kk) {
                short8_t bf = *(const short8_t*)&wvB[m * 4096 + ((kk * 4 + w) * 64 + lane) * 8];
                short8_t af = *(const short8_t*)&HnS[hn_idx(rv, kk * 4 + q)];
                vacc = __builtin_amdgcn_mfma_f32_16x16x32_bf16(af, bf, vacc, 0, 0, 0);
            }
            const float bvv = bv[m * 64 + w * 16 + e];
            floatx4 g = *(const floatx4*)&Sc[w * 432 + m * 16 + q * 4];
            #pragma unroll
            for (int i = 0; i < 4; ++i) o[i] += g[i] * (vacc[i] + bvv);
        }
    }

    // ---- epilogue ----
    const int c = w * 16 + e;
    if (FIRST) {
        #pragma unroll
        for (int i = 0; i < 4; ++i) {
            int n = nb * 16 + q * 4 + i;
            int cell = (n * 32 + a) * 32 + b;
            float xn0 = (x[cell*3+0] - mean0) * rs0;
            float xn1 = (x[cell*3+1] - mean1) * rs1;
            float xn2 = (x[cell*3+2] - mean2) * rs2;
            float res = Waux[192+c] + xn0*Waux[c] + xn1*Waux[64+c] + xn2*Waux[128+c];
            float hv = o[i] + res;
            hout[cell * 64 + c] = hv;
            hbfout[cell * 64 + c] = f2bs(hv);
        }
    } else {
        __syncthreads();                 // all Sc reads done; overlay h_final (pitch 68)
        float* hf = Sc;
        #pragma unroll
        for (int i = 0; i < 4; ++i) {
            int n = nb * 16 + q * 4 + i;
            int cell = (n * 32 + a) * 32 + b;
            hf[(q * 4 + i) * 68 + c] = o[i] + hres[cell * 64 + c];
        }
        __syncthreads();
        if (tid < 48) {
            int row = tid / 3, f = tid - row * 3;
            float acc = Waux[192 + f];
            #pragma unroll 8
            for (int cc = 0; cc < 64; ++cc) acc += hf[row * 68 + cc] * Waux[cc * 3 + f];
            int n = nb * 16 + row;
            out[((n * 32 + a) * 32 + b) * 3 + f] = acc;
        }
    }
}

extern "C" void kernel_launch(void* const* d_in, const int* in_sizes, int n_in,
                              void* d_out, int out_size, void* d_ws, size_t ws_size,
                              hipStream_t stream) {
    const float* x     = (const float*)d_in[0];
    const float* W_in  = (const float*)d_in[1];
    const float* b_in  = (const float*)d_in[2];
    const float* W_out = (const float*)d_in[3];
    const float* b_out = (const float*)d_in[4];
    const float* Wq    = (const float*)d_in[5];
    const float* bq    = (const float*)d_in[6];
    const float* Wk    = (const float*)d_in[7];
    const float* bk    = (const float*)d_in[8];
    const float* Wv    = (const float*)d_in[9];
    const float* bv    = (const float*)d_in[10];

    float* ws    = (float*)d_ws;
    float* stats = ws;                          // 6 floats (sums), pad to 64
    float* h1    = ws + 64;                     // 2M floats (8 MB)
    short* h1bf  = (short*)(h1 + 2097152);      // 2M shorts (4 MB)
    short* wB    = h1bf + 2097152;              // 110 x 4096 bf16 (0.9 MB)

    hipMemsetAsync(stats, 0, 6 * sizeof(float), stream);
    bn_partial<<<32, 256, 0, stream>>>(x, stats);
    repack_all<<<220, 256, 0, stream>>>(Wq, Wk, Wv, wB);

    const short* wq0 = wB;                const short* wq1 = wB + 4096;
    const short* wk0 = wB + 2 * 4096;     const short* wk1 = wB + (2 + 27) * 4096;
    const short* wv0 = wB + 56 * 4096;    const short* wv1 = wB + (56 + 27) * 4096;

    dim3 grid(32, 32, 2);
    layer_fused<true><<<grid, 256, 0, stream>>>(
        x, stats, W_in, b_in, nullptr, nullptr, h1, h1bf,
        nullptr, nullptr, nullptr,
        wq0, bq, wk0, bk, wv0, bv);
    layer_fused<false><<<grid, 256, 0, stream>>>(
        nullptr, nullptr, nullptr, nullptr, h1, h1bf, nullptr, nullptr,
        W_out, b_out, (float*)d_out,
        wq1, bq + 64, wk1, bk + 1728, wv1, bv + 1728);
}

// Round 5
// 174.417 us; speedup vs baseline: 9.8575x; 1.0516x over previous
//
#include <hip/hip_runtime.h>
#include <hip/hip_bf16.h>

// N=32 time, 32x32 grid, C=64 (H=4 x D=16), 3x3x3 offsets (M=27), 2 layers.
// R5: transposed MFMA (A=W^T frag, B=h^T frag) => scores/softmax/V-weights are
// lane-local: 2 shuffles per score, in-register softmax, no Sc LDS, 2 barriers.
// Glue: prep kernel fuses repack + BN partials (no memset, no atomics); 3 launches.

typedef short short8_t __attribute__((ext_vector_type(8)));
typedef float floatx4 __attribute__((ext_vector_type(4)));

__device__ __forceinline__ short f2bs(float f) {
    __hip_bfloat16 h = __float2bfloat16(f);
    return *reinterpret_cast<short*>(&h);
}
// swizzled halo addressing: rowid in [0,162), 8 chunks of 8 shorts, pitch 64
__device__ __forceinline__ int hn_idx(int rowid, int chunk) {
    return rowid * 64 + ((chunk ^ (rowid & 7)) << 3);
}

// ---------------- prep: repack weights + BN partial sums ----------------
// blocks 0..219: repack Wq/Wk/Wv (fp32 [64k][64n]) -> bf16 fragment layout.
//   frag element: dst[mat][((kk*4+nt)*64+lane)*8+j] = W[kk*32+(lane>>4)*8+j][nt*16+(lane&15)]
//   (serves as A-operand W^T[cout][cin] for head nt, k-half kk)
// blocks 220..251: BN partial sums -> sums[blk*8 + {s0,s1,s2,q0,q1,q2}]
__global__ void prep_kernel(const float* __restrict__ Wq, const float* __restrict__ Wk,
                            const float* __restrict__ Wv, short* __restrict__ dst,
                            const float* __restrict__ x, float* __restrict__ sums) {
    if (blockIdx.x < 220) {
        int t = blockIdx.x * 256 + threadIdx.x;
        if (t >= 110 * 512) return;
        int mat  = t >> 9;
        int rem  = t & 511;
        int kk   = rem >> 8;
        int nt   = (rem >> 6) & 3;
        int lane = rem & 63;
        int krow = kk * 32 + (lane >> 4) * 8;
        int col  = nt * 16 + (lane & 15);
        const float* W;
        if (mat < 2)       W = Wq + mat * 4096;
        else if (mat < 56) W = Wk + (mat - 2) * 4096;
        else               W = Wv + (mat - 56) * 4096;
        short8_t v;
        #pragma unroll
        for (int j = 0; j < 8; ++j) v[j] = f2bs(W[(krow + j) * 64 + col]);
        *(short8_t*)&dst[(size_t)mat * 4096 + ((kk * 4 + nt) * 64 + lane) * 8] = v;
    } else {
        int bid = blockIdx.x - 220;
        int t = bid * 256 + threadIdx.x;          // 8192 threads x 3 float4
        const float4* x4 = (const float4*)x;
        float4 v0 = x4[t * 3 + 0], v1 = x4[t * 3 + 1], v2 = x4[t * 3 + 2];
        float vv[6];
        vv[0] = v0.x + v0.w + v1.z + v2.y;
        vv[1] = v0.y + v1.x + v1.w + v2.z;
        vv[2] = v0.z + v1.y + v2.x + v2.w;
        vv[3] = v0.x*v0.x + v0.w*v0.w + v1.z*v1.z + v2.y*v2.y;
        vv[4] = v0.y*v0.y + v1.x*v1.x + v1.w*v1.w + v2.z*v2.z;
        vv[5] = v0.z*v0.z + v1.y*v1.y + v2.x*v2.x + v2.w*v2.w;
        #pragma unroll
        for (int i = 0; i < 6; ++i) {
            #pragma unroll
            for (int off = 1; off < 64; off <<= 1) vv[i] += __shfl_xor(vv[i], off);
        }
        __shared__ float part[4][6];
        if ((threadIdx.x & 63) == 0) {
            #pragma unroll
            for (int i = 0; i < 6; ++i) part[threadIdx.x >> 6][i] = vv[i];
        }
        __syncthreads();
        if (threadIdx.x < 6)
            sums[bid * 8 + threadIdx.x] = part[0][threadIdx.x] + part[1][threadIdx.x] +
                                          part[2][threadIdx.x] + part[3][threadIdx.x];
    }
}

// ---------------- fused attention layer (transposed MFMA) ----------------
// grid (b=32, a=32, nb=2); block 256 = 4 waves; wave w = head w.
// MFMA computes C' = W^T @ h^T : row = d_local (quad*4+reg), col = n (lane&15).
template <bool FIRST>
__global__ __launch_bounds__(256, 4)
void layer_fused(const float* __restrict__ x, const float* __restrict__ sums,
                 const float* __restrict__ W_in, const float* __restrict__ b_in,
                 const float* __restrict__ hres, const short* __restrict__ hbf,
                 float* __restrict__ hout, short* __restrict__ hbfout,
                 const float* __restrict__ Wout, const float* __restrict__ bout,
                 float* __restrict__ out,
                 const short* __restrict__ wqB, const float* __restrict__ bq,
                 const short* __restrict__ wkB, const float* __restrict__ bk,
                 const short* __restrict__ wvB, const float* __restrict__ bv) {
    __shared__ short HnS[162 * 64];   // 20.25 KB, XOR-swizzled; reused as hf in LAST epilogue
    __shared__ float Waux[256];       // FIRST: W_in[3][64]+b_in[64]; LAST: Wout[64*3]+bout[3]
    __shared__ float bn6[6];          // mean[3], rstd[3]

    const int tid = threadIdx.x;
    const int b = blockIdx.x, a = blockIdx.y, nb = blockIdx.z;

    if (FIRST) {
        if (tid < 3) {
            float s = 0.f, qq = 0.f;
            #pragma unroll
            for (int p = 0; p < 32; ++p) { s += sums[p * 8 + tid]; qq += sums[p * 8 + 3 + tid]; }
            float mean = s * (1.f / 32768.f);
            float var  = qq * (1.f / 32768.f) - mean * mean;
            bn6[tid]     = mean;
            bn6[3 + tid] = rsqrtf(var + 1e-5f);
        }
        if (tid < 192) Waux[tid] = W_in[tid];
        else           Waux[tid] = b_in[tid - 192];
    } else {
        if (tid < 192)      Waux[tid] = Wout[tid];
        else if (tid < 195) Waux[tid] = bout[tid - 192];
    }
    __syncthreads();

    float mean0, mean1, mean2, rs0, rs1, rs2;
    if (FIRST) {
        mean0 = bn6[0]; mean1 = bn6[1]; mean2 = bn6[2];
        rs0 = bn6[3]; rs1 = bn6[4]; rs2 = bn6[5];
    }

    // ---- stage halo: 162 rows x 8 chunks of 8 bf16 ----
    for (int id = tid; id < 1296; id += 256) {
        int rowid = id >> 3, cc = id & 7;
        int sp = rowid / 18, r = rowid - sp * 18;
        int aa = a + sp / 3 - 1, bb = b + sp % 3 - 1;
        int n  = nb * 16 + r - 1;
        short8_t v = {0, 0, 0, 0, 0, 0, 0, 0};
        if ((unsigned)n < 32u && (unsigned)aa < 32u && (unsigned)bb < 32u) {
            int cell = (n * 32 + aa) * 32 + bb;
            if (FIRST) {
                float xn0 = (x[cell*3+0] - mean0) * rs0;
                float xn1 = (x[cell*3+1] - mean1) * rs1;
                float xn2 = (x[cell*3+2] - mean2) * rs2;
                #pragma unroll
                for (int j = 0; j < 8; ++j) {
                    int c = cc * 8 + j;
                    float h = Waux[192+c] + xn0*Waux[c] + xn1*Waux[64+c] + xn2*Waux[128+c];
                    v[j] = f2bs(h);
                }
            } else {
                v = *(const short8_t*)&hbf[cell * 64 + cc * 8];
            }
        }
        *(short8_t*)&HnS[hn_idx(rowid, cc)] = v;
    }
    __syncthreads();

    const int lane = tid & 63;
    const int w    = tid >> 6;       // head
    const int e    = lane & 15;      // column n (local time row)
    const int q    = lane >> 4;      // quad: d_local = q*4 + reg
    const int c0   = w * 16 + q * 4; // global channel base for this lane's regs

    // ---- Q^T projection (center cell sp=4, col n=e) ----
    floatx4 qacc = {0, 0, 0, 0};
    {
        const int rq = 4 * 18 + e + 1;
        #pragma unroll
        for (int kk = 0; kk < 2; ++kk) {
            short8_t wf = *(const short8_t*)&wqB[((kk * 4 + w) * 64 + lane) * 8];
            short8_t hf = *(const short8_t*)&HnS[hn_idx(rq, kk * 4 + q)];
            qacc = __builtin_amdgcn_mfma_f32_16x16x32_bf16(wf, hf, qacc, 0, 0, 0);
        }
    }
    const float4 bq4 = *(const float4*)&bq[c0];
    float qv[4] = {qacc[0] + bq4.x, qacc[1] + bq4.y, qacc[2] + bq4.z, qacc[3] + bq4.w};

    // ---- K pass: in-register scores ----
    float sc[27];
    #pragma unroll
    for (int sp = 0; sp < 9; ++sp) {
        const bool valid = ((unsigned)(a + sp / 3 - 1) < 32u) &&
                           ((unsigned)(b + sp % 3 - 1) < 32u);
        #pragma unroll
        for (int t = 0; t < 3; ++t) {
            const int m = t * 9 + sp;
            if (valid) {
                floatx4 kacc = {0, 0, 0, 0};
                const int rk = sp * 18 + e + t;
                #pragma unroll
                for (int kk = 0; kk < 2; ++kk) {
                    short8_t wf = *(const short8_t*)&wkB[m * 4096 + ((kk * 4 + w) * 64 + lane) * 8];
                    short8_t hf = *(const short8_t*)&HnS[hn_idx(rk, kk * 4 + q)];
                    kacc = __builtin_amdgcn_mfma_f32_16x16x32_bf16(wf, hf, kacc, 0, 0, 0);
                }
                const float4 bk4 = *(const float4*)&bk[m * 64 + c0];
                float p = (kacc[0] + bk4.x) * qv[0] + (kacc[1] + bk4.y) * qv[1]
                        + (kacc[2] + bk4.z) * qv[2] + (kacc[3] + bk4.w) * qv[3];
                p += __shfl_xor(p, 16);
                p += __shfl_xor(p, 32);
                sc[m] = p;
            } else {
                sc[m] = -1e30f;
            }
        }
    }

    // ---- softmax over 27, fully in-register ----
    float mx = sc[0];
    #pragma unroll
    for (int m = 1; m < 27; ++m) mx = fmaxf(mx, sc[m]);
    float ssum = 0.f;
    #pragma unroll
    for (int m = 0; m < 27; ++m) { sc[m] = __expf(sc[m] - mx); ssum += sc[m]; }
    float sinv = 1.0f / ssum;

    // ---- V pass: lane-local weighted accumulate ----
    floatx4 o = {0, 0, 0, 0};
    #pragma unroll
    for (int sp = 0; sp < 9; ++sp) {
        if (!(((unsigned)(a + sp / 3 - 1) < 32u) &&
              ((unsigned)(b + sp % 3 - 1) < 32u))) continue;
        #pragma unroll
        for (int t = 0; t < 3; ++t) {
            const int m = t * 9 + sp;
            floatx4 vacc = {0, 0, 0, 0};
            const int rv = sp * 18 + e + t;
            #pragma unroll
            for (int kk = 0; kk < 2; ++kk) {
                short8_t wf = *(const short8_t*)&wvB[m * 4096 + ((kk * 4 + w) * 64 + lane) * 8];
                short8_t hf = *(const short8_t*)&HnS[hn_idx(rv, kk * 4 + q)];
                vacc = __builtin_amdgcn_mfma_f32_16x16x32_bf16(wf, hf, vacc, 0, 0, 0);
            }
            const float4 bv4 = *(const float4*)&bv[m * 64 + c0];
            const float wgt = sc[m] * sinv;
            o[0] += wgt * (vacc[0] + bv4.x);
            o[1] += wgt * (vacc[1] + bv4.y);
            o[2] += wgt * (vacc[2] + bv4.z);
            o[3] += wgt * (vacc[3] + bv4.w);
        }
    }

    // ---- epilogue: lane owns row n = nb*16+e, channels c0..c0+3 ----
    const int n = nb * 16 + e;
    const int cell = (n * 32 + a) * 32 + b;
    if (FIRST) {
        float xn0 = (x[cell*3+0] - mean0) * rs0;
        float xn1 = (x[cell*3+1] - mean1) * rs1;
        float xn2 = (x[cell*3+2] - mean2) * rs2;
        float4 hv;
        float* hvp = (float*)&hv;
        short4 hb;
        short* hbp = (short*)&hb;
        #pragma unroll
        for (int i = 0; i < 4; ++i) {
            int c = c0 + i;
            float res = Waux[192+c] + xn0*Waux[c] + xn1*Waux[64+c] + xn2*Waux[128+c];
            float v = o[i] + res;
            hvp[i] = v;
            hbp[i] = f2bs(v);
        }
        *(float4*)&hout[cell * 64 + c0] = hv;
        *(short4*)&hbfout[cell * 64 + c0] = hb;
    } else {
        float4 res = *(const float4*)&hres[cell * 64 + c0];
        __syncthreads();                   // all HnS reads done; overlay h_final
        float* hf = (float*)HnS;           // [16 rows][pitch 68]
        hf[e * 68 + c0 + 0] = o[0] + res.x;
        hf[e * 68 + c0 + 1] = o[1] + res.y;
        hf[e * 68 + c0 + 2] = o[2] + res.z;
        hf[e * 68 + c0 + 3] = o[3] + res.w;
        __syncthreads();
        if (tid < 48) {
            int row = tid / 3, f = tid - row * 3;
            float acc = Waux[192 + f];
            #pragma unroll 8
            for (int cc = 0; cc < 64; ++cc) acc += hf[row * 68 + cc] * Waux[cc * 3 + f];
            int nn = nb * 16 + row;
            out[((nn * 32 + a) * 32 + b) * 3 + f] = acc;
        }
    }
}

extern "C" void kernel_launch(void* const* d_in, const int* in_sizes, int n_in,
                              void* d_out, int out_size, void* d_ws, size_t ws_size,
                              hipStream_t stream) {
    const float* x     = (const float*)d_in[0];
    const float* W_in  = (const float*)d_in[1];
    const float* b_in  = (const float*)d_in[2];
    const float* W_out = (const float*)d_in[3];
    const float* b_out = (const float*)d_in[4];
    const float* Wq    = (const float*)d_in[5];
    const float* bq    = (const float*)d_in[6];
    const float* Wk    = (const float*)d_in[7];
    const float* bk    = (const float*)d_in[8];
    const float* Wv    = (const float*)d_in[9];
    const float* bv    = (const float*)d_in[10];

    float* ws    = (float*)d_ws;
    float* sums  = ws;                          // 32 x 8 floats (BN partials)
    float* h1    = ws + 256;                    // 2M floats (8 MB)
    short* h1bf  = (short*)(h1 + 2097152);      // 2M shorts (4 MB)
    short* wB    = h1bf + 2097152;              // 110 x 4096 bf16 (0.9 MB)

    prep_kernel<<<252, 256, 0, stream>>>(Wq, Wk, Wv, wB, x, sums);

    const short* wq0 = wB;                const short* wq1 = wB + 4096;
    const short* wk0 = wB + 2 * 4096;     const short* wk1 = wB + (2 + 27) * 4096;
    const short* wv0 = wB + 56 * 4096;    const short* wv1 = wB + (56 + 27) * 4096;

    dim3 grid(32, 32, 2);
    layer_fused<true><<<grid, 256, 0, stream>>>(
        x, sums, W_in, b_in, nullptr, nullptr, h1, h1bf,
        nullptr, nullptr, nullptr,
        wq0, bq, wk0, bk, wv0, bv);
    layer_fused<false><<<grid, 256, 0, stream>>>(
        nullptr, nullptr, nullptr, nullptr, h1, h1bf, nullptr, nullptr,
        W_out, b_out, (float*)d_out,
        wq1, bq + 64, wk1, bk + 1728, wv1, bv + 1728);
}